// Round 2
// baseline (594.597 us; speedup 1.0000x reference)
//
#include <hip/hip_runtime.h>

#define D_     512
#define H_     8
#define NCOLS_ 2048
#define DCOL_  22
#define B_     8
#define NKEEP_ 768
#define T_     769
#define BT_    (B_*T_)   // 6152
#define BH_    (B_*H_)   // 64

typedef __attribute__((ext_vector_type(8))) short bf16x8;
typedef __attribute__((ext_vector_type(8))) _Float16 f16x8;
typedef __attribute__((ext_vector_type(4))) float f32x4;

__device__ __forceinline__ ushort f2bf(float f) {
    unsigned u = __float_as_uint(f);
    unsigned r = u + 0x7fffu + ((u >> 16) & 1u);   // RNE
    return (ushort)(r >> 16);
}
__device__ __forceinline__ float bf2f(ushort u) {
    return __uint_as_float(((unsigned)u) << 16);
}

// Exact fp32 gate dot (same arithmetic/order as the original passing kernel).
// noinline: called only on the rare |score| <= margin path.
__device__ __attribute__((noinline)) float exact_dot22(
    const float* __restrict__ qp, const float* __restrict__ kp)
{
    float s = 0.f;
    #pragma unroll
    for (int d2 = 0; d2 < DCOL_; ++d2) s += qp[d2]*kp[d2];
    return s;
}

// ---------------------------------------------------------------------------
// Projections: C[M,512] = A[M,512] @ W[512,512]^T + bias  (bf16 MFMA)
// ---------------------------------------------------------------------------
__global__ __launch_bounds__(256) void proj_mfma(
    const float* __restrict__ xh, const float* __restrict__ xt,
    const ushort* __restrict__ x1b,
    const float* __restrict__ Wh, const float* __restrict__ Wv,
    const float* __restrict__ Wo,
    const float* __restrict__ bh_, const float* __restrict__ bv_,
    const float* __restrict__ bo_, const float* __restrict__ rel,
    ushort* __restrict__ fhb, ushort* __restrict__ ftb,
    ushort* __restrict__ fvb, float* __restrict__ xout, const int jobParam)
{
    __shared__ __align__(16) ushort As[128*40];
    __shared__ __align__(16) ushort Bs[128*40];
    const int job = (jobParam < 0) ? (int)blockIdx.z : jobParam;
    const float* A32 = nullptr; const ushort* A16 = nullptr;
    const float* W; const float* bias;
    ushort* outb = nullptr; float* outf = nullptr; int mode;
    if (job == 0)      { A32 = xh; W = Wh; bias = bh_; outb = fhb; mode = 0; }
    else if (job == 1) { A32 = xt; W = Wh; bias = bh_; outb = ftb; mode = 1; }
    else if (job == 2) { A32 = xt; W = Wv; bias = bv_; outb = fvb; mode = 2; }
    else               { A16 = x1b; W = Wo; bias = bo_; outf = xout; mode = 3; }

    const int t    = threadIdx.x;
    const int lane = t & 63;
    const int wv   = t >> 6;
    const int wr   = wv >> 1, wc = wv & 1;
    const int m16  = lane & 15, q4 = lane >> 4;
    const int m0   = blockIdx.y * 128;
    const int n0   = blockIdx.x * 128;

    f32x4 acc[4][4] = {};
    for (int k0 = 0; k0 < 512; k0 += 32) {
        {
            const int sr = t >> 1, sh = t & 1;
            const int row = m0 + sr;
            ushort ta[16];
            if (A16) {
                bf16x8 z = {}; bf16x8 v0 = z, v1 = z;
                if (row < BT_) {
                    const bf16x8* gp = (const bf16x8*)(A16 + (size_t)row*512 + k0 + sh*16);
                    v0 = gp[0]; v1 = gp[1];
                }
                *(bf16x8*)&ta[0] = v0; *(bf16x8*)&ta[8] = v1;
            } else {
                #pragma unroll
                for (int e = 0; e < 16; ++e) ta[e] = 0;
                if (row < BT_) {
                    const float* ap = A32 + (size_t)row*512 + k0 + sh*16;
                    #pragma unroll
                    for (int e = 0; e < 4; ++e) {
                        float4 f = *(const float4*)(ap + e*4);
                        ta[e*4+0]=f2bf(f.x); ta[e*4+1]=f2bf(f.y);
                        ta[e*4+2]=f2bf(f.z); ta[e*4+3]=f2bf(f.w);
                    }
                }
            }
            *(bf16x8*)&As[sr*40 + sh*16]     = *(bf16x8*)&ta[0];
            *(bf16x8*)&As[sr*40 + sh*16 + 8] = *(bf16x8*)&ta[8];
            const float* wp = W + (size_t)(n0 + sr)*512 + k0 + sh*16;
            ushort tw[16];
            #pragma unroll
            for (int e = 0; e < 4; ++e) {
                float4 f = *(const float4*)(wp + e*4);
                tw[e*4+0]=f2bf(f.x); tw[e*4+1]=f2bf(f.y);
                tw[e*4+2]=f2bf(f.z); tw[e*4+3]=f2bf(f.w);
            }
            *(bf16x8*)&Bs[sr*40 + sh*16]     = *(bf16x8*)&tw[0];
            *(bf16x8*)&Bs[sr*40 + sh*16 + 8] = *(bf16x8*)&tw[8];
        }
        __syncthreads();
        bf16x8 a[4], b[4];
        #pragma unroll
        for (int i = 0; i < 4; ++i)
            a[i] = *(const bf16x8*)&As[(wr*64 + i*16 + m16)*40 + q4*8];
        #pragma unroll
        for (int j = 0; j < 4; ++j)
            b[j] = *(const bf16x8*)&Bs[(wc*64 + j*16 + m16)*40 + q4*8];
        #pragma unroll
        for (int i = 0; i < 4; ++i)
            #pragma unroll
            for (int j = 0; j < 4; ++j)
                acc[i][j] = __builtin_amdgcn_mfma_f32_16x16x32_bf16(a[i], b[j], acc[i][j], 0, 0, 0);
        __syncthreads();
    }

    #pragma unroll
    for (int j = 0; j < 4; ++j) {
        const int n = n0 + wc*64 + j*16 + m16;
        const float bn = bias[n];
        const float sc = (mode == 0) ? rel[n] * 0.125f : 1.0f;
        const int h = n >> 6, dh = n & 63;
        #pragma unroll
        for (int i = 0; i < 4; ++i) {
            #pragma unroll
            for (int r = 0; r < 4; ++r) {
                int m = m0 + wr*64 + i*16 + q4*4 + r;
                if (m >= BT_) continue;
                float v = acc[i][j][r] + bn;
                if (mode == 3) {
                    outf[(size_t)m*512 + n] = v;
                } else {
                    if (mode == 0) v *= sc;
                    int bb = m / T_, tt = m - bb*T_;
                    outb[(((size_t)bb*H_ + h)*T_ + tt)*64 + dh] = f2bf(v);
                }
            }
        }
    }
}

// ---------------------------------------------------------------------------
// Normalize col rows, gather per ids_keep (fp32, exact) AND emit f16 hi/lo
// split (x*32 = hi + lo/2048) padded to 32 dims for the MFMA gate.
// ---------------------------------------------------------------------------
__global__ void gather_norm(
    const float* __restrict__ col_head, const float* __restrict__ col_tail,
    const int* __restrict__ ids, float* __restrict__ chg, float* __restrict__ ctg,
    ushort* __restrict__ chH, ushort* __restrict__ chL,
    ushort* __restrict__ ctH, ushort* __restrict__ ctL)
{
    int r = blockIdx.x * blockDim.x + threadIdx.x;
    const int total = BH_ * T_;
    if (r >= 2*total) return;
    const bool tail = (r >= total);
    int rr = tail ? r - total : r;
    int bh = rr / T_;
    int q  = rr - bh*T_;
    int b  = bh >> 3, h = bh & 7;
    int src = (q == 0) ? 0 : (1 + ids[b*NKEEP_ + q - 1]);
    const float* cp = (tail ? col_tail : col_head) + ((size_t)h*NCOLS_ + src)*DCOL_;
    float v[DCOL_];
    float ss = 0.f;
    #pragma unroll
    for (int j = 0; j < DCOL_; ++j) { v[j] = cp[j]; ss += v[j]*v[j]; }
    float inv = 1.0f / sqrtf(ss);
    float* op = (tail ? ctg : chg) + (size_t)rr*DCOL_;
    ushort* hp = (tail ? ctH : chH) + (size_t)rr*32;
    ushort* lp = (tail ? ctL : chL) + (size_t)rr*32;
    #pragma unroll
    for (int j = 0; j < DCOL_; ++j) {
        float x = v[j]*inv;
        op[j] = x;
        float xs = x * 32.f;
        _Float16 hh = (_Float16)xs;
        float res = (xs - (float)hh) * 2048.f;
        _Float16 ll = (_Float16)res;
        hp[j] = __builtin_bit_cast(ushort, hh);
        lp[j] = __builtin_bit_cast(ushort, ll);
    }
    #pragma unroll
    for (int j = DCOL_; j < 32; ++j) { hp[j] = 0; lp[j] = 0; }
}

// ---------------------------------------------------------------------------
// Fused gate+score+exp+rowsum+PV.
//  - gate via f16 hi/lo double-MFMA (scaled x32; score*1024 = G1 + G2/2048),
//    margin 0.16 (=1.56e-4 on true score) -> exact fp32 recompute (rare)
//  - Vs transpose scatter XOR-swizzled on 16B k-granules (kills 8-way conflict)
//  - async-stage split: next tile's global loads issued before compute barrier
//  - NO XCD block swizzle: identity mapping measured 71 MB fetch vs 294 MB
//    with the %8-chunk remap (R1 post-mortem: remap broke natural placement,
//    fr half-line evictions doubled write traffic).
// ---------------------------------------------------------------------------
__global__ __launch_bounds__(256, 3) void fused_attn(
    const ushort* __restrict__ fhb, const ushort* __restrict__ ftb,
    const ushort* __restrict__ fvb, const float* __restrict__ chg,
    const float* __restrict__ ctg,
    const ushort* __restrict__ chH, const ushort* __restrict__ chL,
    const ushort* __restrict__ ctH, const ushort* __restrict__ ctL,
    const float* __restrict__ biasp,
    float* __restrict__ fr, ushort* __restrict__ x1b, float* __restrict__ invA)
{
    __shared__ __align__(16) ushort Qs[64*72];
    __shared__ __align__(16) ushort Ks[64*72];
    __shared__ __align__(16) ushort Vs[64*72];   // transposed [d][k], k-granule swizzled
    __shared__ __align__(16) ushort Et[64*72];   // e tile [q][k]
    __shared__ __align__(16) ushort KH[64*40];   // gate K hi (f16, 32 dims + pad)
    __shared__ __align__(16) ushort KL[64*40];   // gate K lo
    __shared__ float sumP[4*64];
    __shared__ float inv_s[64];

    const int bh = blockIdx.y;
    const int q0 = blockIdx.x * 64;

    const int t    = threadIdx.x;
    const int lane = t & 63, w = t >> 6;
    const int m16  = lane & 15, q4 = lane >> 4;
    const float bias0 = biasp[0];

    // ---- prefetch registers (T14 async-stage split) ----
    const int pkr = t >> 2, pqt = t & 3;
    bf16x8 pK0, pK1, pV0, pV1, pH, pL;
    auto issue_tile = [&](int kt) {
        int kc = min(kt*64 + pkr, T_-1);
        const ushort* kp = ftb + ((size_t)bh*T_ + kc)*64 + pqt*16;
        pK0 = *(const bf16x8*)kp; pK1 = *(const bf16x8*)(kp + 8);
        const ushort* vp = fvb + ((size_t)bh*T_ + kc)*64 + pqt*16;
        pV0 = *(const bf16x8*)vp; pV1 = *(const bf16x8*)(vp + 8);
        pH = *(const bf16x8*)(ctH + ((size_t)bh*T_ + kc)*32 + pqt*8);
        pL = *(const bf16x8*)(ctL + ((size_t)bh*T_ + kc)*32 + pqt*8);
    };
    issue_tile(0);

    // stage Q strip (64 x 64 bf16) once
    {
        int qr = t >> 2, qc = min(q0 + qr, T_-1);
        const ushort* qp = fhb + ((size_t)bh*T_ + qc)*64 + (t&3)*16;
        *(bf16x8*)&Qs[qr*72 + (t&3)*16]     = *(const bf16x8*)qp;
        *(bf16x8*)&Qs[qr*72 + (t&3)*16 + 8] = *(const bf16x8*)(qp + 8);
    }
    // gate Q fragments (f16 hi/lo) live in registers for the whole kernel
    f16x8 gqh[4], gql[4];
    #pragma unroll
    for (int i = 0; i < 4; ++i) {
        int qc = min(q0 + i*16 + m16, T_-1);
        gqh[i] = *(const f16x8*)(chH + ((size_t)bh*T_ + qc)*32 + q4*8);
        gql[i] = *(const f16x8*)(chL + ((size_t)bh*T_ + qc)*32 + q4*8);
    }

    float psum[4][4] = {};
    f32x4 Oacc[4] = {};

    for (int kt = 0; kt < 13; ++kt) {
        const int k0g = kt*64;
        __syncthreads();   // prior tile's Et/Vs/Ks consumers done (also covers Qs on kt=0)

        // commit prefetched regs -> LDS
        *(bf16x8*)&Ks[pkr*72 + pqt*16]     = pK0;
        *(bf16x8*)&Ks[pkr*72 + pqt*16 + 8] = pK1;
        {
            const int dbase = pqt*16;
            #pragma unroll
            for (int e = 0; e < 8; ++e) {
                int d = dbase + e;
                Vs[d*72 + (((pkr>>3) ^ (d>>3))<<3) + (pkr&7)] = (ushort)pV0[e];
            }
            #pragma unroll
            for (int e = 0; e < 8; ++e) {
                int d = dbase + 8 + e;
                Vs[d*72 + (((pkr>>3) ^ (d>>3))<<3) + (pkr&7)] = (ushort)pV1[e];
            }
        }
        *(bf16x8*)&KH[pkr*40 + pqt*8] = pH;
        *(bf16x8*)&KL[pkr*40 + pqt*8] = pL;

        if (kt + 1 < 13) issue_tile(kt + 1);   // overlaps gate+QK+PV below
        __syncthreads();

        // ---- gate: f16 hi/lo double-MFMA, score*1024 = G1 + G2/2048 ----
        const int kL2 = w*16 + m16;
        const int kg  = k0g + kL2;
        unsigned kmask = 0;
        {
            f16x8 bhf = *(const f16x8*)&KH[kL2*40 + q4*8];
            f16x8 blf = *(const f16x8*)&KL[kL2*40 + q4*8];
            f32x4 G1[4] = {}; f32x4 G2[4] = {};
            #pragma unroll
            for (int i = 0; i < 4; ++i) {
                G1[i] = __builtin_amdgcn_mfma_f32_16x16x32_f16(gqh[i], bhf, G1[i], 0, 0, 0);
                G2[i] = __builtin_amdgcn_mfma_f32_16x16x32_f16(gqh[i], blf, G2[i], 0, 0, 0);
                G2[i] = __builtin_amdgcn_mfma_f32_16x16x32_f16(gql[i], bhf, G2[i], 0, 0, 0);
            }
            const bool kok = (kg != 0) && (kg < T_);
            if (kok) {
                const float bS = bias0 * 1024.f;
                #pragma unroll
                for (int i = 0; i < 4; ++i) {
                    #pragma unroll
                    for (int r = 0; r < 4; ++r) {
                        int qg = q0 + i*16 + q4*4 + r;
                        if (qg == kg) continue;
                        float sd = G1[i][r] + G2[i][r]*(1.0f/2048.0f) + bS;
                        bool keep = sd > 0.f;
                        if (__builtin_fabsf(sd) <= 0.16f && qg < T_) {
                            float s = exact_dot22(chg + ((size_t)bh*T_ + qg)*DCOL_,
                                                  ctg + ((size_t)bh*T_ + kg)*DCOL_);
                            keep = (s + bias0 > 0.f);
                        }
                        if (keep) kmask |= 1u << (i*4 + r);
                    }
                }
            }
        }

        // ---- QK^T MFMA (S tile: 64q x 16k-slice per wave) ----
        f32x4 Sacc[4] = {};
        #pragma unroll
        for (int step = 0; step < 2; ++step) {
            bf16x8 b = *(const bf16x8*)&Ks[kL2*72 + step*32 + q4*8];
            #pragma unroll
            for (int i = 0; i < 4; ++i) {
                bf16x8 a = *(const bf16x8*)&Qs[(i*16 + m16)*72 + step*32 + q4*8];
                Sacc[i] = __builtin_amdgcn_mfma_f32_16x16x32_bf16(a, b, Sacc[i], 0, 0, 0);
            }
        }

        // ---- e = keep ? exp(s) : 0 ; rowsums; Et (bf16) ----
        #pragma unroll
        for (int i = 0; i < 4; ++i) {
            #pragma unroll
            for (int r = 0; r < 4; ++r) {
                float e = ((kmask >> (i*4 + r)) & 1u) ? __expf(Sacc[i][r]) : 0.f;
                psum[i][r] += e;
                Et[(i*16 + q4*4 + r)*72 + kL2] = f2bf(e);
            }
        }
        __syncthreads();

        // ---- PV MFMA: wave w accumulates O rows w*16..+15 over 64 d ----
        #pragma unroll
        for (int step = 0; step < 2; ++step) {
            bf16x8 a = *(const bf16x8*)&Et[(w*16 + m16)*72 + step*32 + q4*8];
            #pragma unroll
            for (int j = 0; j < 4; ++j) {
                int dv = j*16 + m16;
                bf16x8 b = *(const bf16x8*)&Vs[dv*72 + (((step*4 + q4) ^ (dv>>3))<<3)];
                Oacc[j] = __builtin_amdgcn_mfma_f32_16x16x32_bf16(a, b, Oacc[j], 0, 0, 0);
            }
        }

        // ---- Et tile -> packed bf16 prefix of fr rows ----
        {
            const int c = t & 15;
            #pragma unroll
            for (int p = 0; p < 4; ++p) {
                int row = p*16 + (t >> 4);
                int qg = q0 + row;
                if (qg >= T_) continue;
                char* rowbase = (char*)(fr + ((size_t)bh*T_ + qg)*T_);
                #pragma unroll
                for (int e = 0; e < 2; ++e) {
                    int dw = c + 16*e;
                    int kk = k0g + dw*2;
                    unsigned u = *(const unsigned*)&Et[row*72 + dw*2];
                    if (kk + 1 < T_)      *(unsigned*)(rowbase + (size_t)kk*2) = u;
                    else if (kk < T_)     *(ushort*)(rowbase + (size_t)kk*2) = (ushort)u;
                }
            }
        }
    }

    // reduce rowsums over the 16 k-columns (m16) per wave
    #pragma unroll
    for (int i = 0; i < 4; ++i)
        #pragma unroll
        for (int r = 0; r < 4; ++r) {
            float v = psum[i][r];
            v += __shfl_xor(v, 1, 64);
            v += __shfl_xor(v, 2, 64);
            v += __shfl_xor(v, 4, 64);
            v += __shfl_xor(v, 8, 64);
            psum[i][r] = v;
        }
    if (m16 == 0) {
        #pragma unroll
        for (int i = 0; i < 4; ++i)
            #pragma unroll
            for (int r = 0; r < 4; ++r)
                sumP[w*64 + i*16 + q4*4 + r] = psum[i][r];
    }
    __syncthreads();
    if (t < 64) {
        float s = sumP[t] + sumP[64+t] + sumP[128+t] + sumP[192+t];
        float iv = 1.0f / fmaxf(s, 1e-30f);
        inv_s[t] = iv;
        if (q0 + t < T_) invA[(size_t)bh*T_ + q0 + t] = iv;
    }
    __syncthreads();

    // O epilogue: normalize + store x1 (bf16)
    {
        const int b = bh >> 3, h = bh & 7;
        #pragma unroll
        for (int j = 0; j < 4; ++j) {
            int d = j*16 + m16;
            #pragma unroll
            for (int r = 0; r < 4; ++r) {
                int rr = w*16 + q4*4 + r;
                int qg = q0 + rr;
                if (qg < T_)
                    x1b[((size_t)b*T_ + qg)*512 + h*64 + d] = f2bf(Oacc[j][r] * inv_s[rr]);
            }
        }
    }
}

// ---------------------------------------------------------------------------
__global__ __launch_bounds__(256) void normalize_fr(
    float* __restrict__ fr, const float* __restrict__ invA)
{
    const int row = blockIdx.x;
    const int t = threadIdx.x;
    float* rowp = fr + (size_t)row * T_;
    const ushort* packed = (const ushort*)rowp;
    const float iv = invA[row];
    float v0 = bf2f(packed[t])       * iv;
    float v1 = bf2f(packed[t + 256]) * iv;
    float v2 = bf2f(packed[t + 512]) * iv;
    float v3 = 0.f;
    if (t == 0) v3 = bf2f(packed[768]) * iv;
    __syncthreads();
    rowp[t]       = v0;
    rowp[t + 256] = v1;
    rowp[t + 512] = v2;
    if (t == 0) rowp[768] = v3;
}

// ---------------------------------------------------------------------------
extern "C" void kernel_launch(void* const* d_in, const int* in_sizes, int n_in,
                              void* d_out, int out_size, void* d_ws, size_t ws_size,
                              hipStream_t stream)
{
    (void)in_sizes; (void)n_in; (void)out_size; (void)ws_size;
    const float* x_head   = (const float*)d_in[0];
    const float* x_tail   = (const float*)d_in[1];
    const int*   ids      = (const int*)  d_in[2];
    const float* W_head_w = (const float*)d_in[3];
    const float* W_head_b = (const float*)d_in[4];
    const float* W_v_w    = (const float*)d_in[5];
    const float* W_v_b    = (const float*)d_in[6];
    const float* W_out_w  = (const float*)d_in[7];
    const float* W_out_b  = (const float*)d_in[8];
    const float* rel      = (const float*)d_in[9];
    const float* col_h    = (const float*)d_in[10];
    const float* col_t    = (const float*)d_in[11];
    const float* biasp    = (const float*)d_in[12];

    const size_t F   = (size_t)BH_*T_*64;       // 3,149,824
    const size_t C22 = (size_t)BH_*T_*DCOL_;
    const size_t C32 = (size_t)BH_*T_*32;

    char* ws = (char*)d_ws;
    ushort* fhb = (ushort*)ws;   ws += F*2;
    ushort* ftb = (ushort*)ws;   ws += F*2;
    ushort* fvb = (ushort*)ws;   ws += F*2;
    ushort* x1b = (ushort*)ws;   ws += F*2;
    float*  chg = (float*)ws;    ws += C22*4;
    float*  ctg = (float*)ws;    ws += C22*4;
    float*  invA = (float*)ws;   ws += (size_t)BH_*T_*4;
    ushort* chH = (ushort*)ws;   ws += C32*2;
    ushort* chL = (ushort*)ws;   ws += C32*2;
    ushort* ctH = (ushort*)ws;   ws += C32*2;
    ushort* ctL = (ushort*)ws;   ws += C32*2;

    float* xout = (float*)d_out;
    float* fr   = xout + (size_t)BT_*D_;

    dim3 blk(256, 1, 1);

    gather_norm<<<(2*BH_*T_ + 255)/256, blk, 0, stream>>>(
        col_h, col_t, ids, chg, ctg, chH, chL, ctH, ctL);

    proj_mfma<<<dim3(4, 49, 3), blk, 0, stream>>>(
        x_head, x_tail, nullptr, W_head_w, W_v_w, W_out_w,
        W_head_b, W_v_b, W_out_b, rel, fhb, ftb, fvb, nullptr, -1);

    fused_attn<<<dim3(13, BH_), blk, 0, stream>>>(
        fhb, ftb, fvb, chg, ctg, chH, chL, ctH, ctL, biasp, fr, x1b, invA);

    normalize_fr<<<BH_*T_, blk, 0, stream>>>(fr, invA);

    proj_mfma<<<dim3(4, 49, 1), blk, 0, stream>>>(
        x_head, x_tail, x1b, W_head_w, W_v_w, W_out_w,
        W_head_b, W_v_b, W_out_b, rel, fhb, ftb, fvb, xout, 3);
}

// Round 5
// 491.929 us; speedup vs baseline: 1.2087x; 1.2087x over previous
//
#include <hip/hip_runtime.h>

#define D_     512
#define H_     8
#define NCOLS_ 2048
#define DCOL_  22
#define B_     8
#define NKEEP_ 768
#define T_     769
#define BT_    (B_*T_)   // 6152
#define BH_    (B_*H_)   // 64

typedef __attribute__((ext_vector_type(8))) short bf16x8;
typedef __attribute__((ext_vector_type(8))) _Float16 f16x8;
typedef __attribute__((ext_vector_type(4))) float f32x4;

__device__ __forceinline__ ushort f2bf(float f) {
    unsigned u = __float_as_uint(f);
    unsigned r = u + 0x7fffu + ((u >> 16) & 1u);   // RNE
    return (ushort)(r >> 16);
}
__device__ __forceinline__ float bf2f(ushort u) {
    return __uint_as_float(((unsigned)u) << 16);
}

// Exact fp32 gate dot (same arithmetic/order as the original passing kernel).
// noinline: called only on the rare |score| <= margin path.
__device__ __attribute__((noinline)) float exact_dot22(
    const float* __restrict__ qp, const float* __restrict__ kp)
{
    float s = 0.f;
    #pragma unroll
    for (int d2 = 0; d2 < DCOL_; ++d2) s += qp[d2]*kp[d2];
    return s;
}

// ---------------------------------------------------------------------------
// Projections: C[M,512] = A[M,512] @ W[512,512]^T + bias  (bf16 MFMA)
// ---------------------------------------------------------------------------
__global__ __launch_bounds__(256) void proj_mfma(
    const float* __restrict__ xh, const float* __restrict__ xt,
    const ushort* __restrict__ x1b,
    const float* __restrict__ Wh, const float* __restrict__ Wv,
    const float* __restrict__ Wo,
    const float* __restrict__ bh_, const float* __restrict__ bv_,
    const float* __restrict__ bo_, const float* __restrict__ rel,
    ushort* __restrict__ fhb, ushort* __restrict__ ftb,
    ushort* __restrict__ fvb, float* __restrict__ xout, const int jobParam)
{
    __shared__ __align__(16) ushort As[128*40];
    __shared__ __align__(16) ushort Bs[128*40];
    const int job = (jobParam < 0) ? (int)blockIdx.z : jobParam;
    const float* A32 = nullptr; const ushort* A16 = nullptr;
    const float* W; const float* bias;
    ushort* outb = nullptr; float* outf = nullptr; int mode;
    if (job == 0)      { A32 = xh; W = Wh; bias = bh_; outb = fhb; mode = 0; }
    else if (job == 1) { A32 = xt; W = Wh; bias = bh_; outb = ftb; mode = 1; }
    else if (job == 2) { A32 = xt; W = Wv; bias = bv_; outb = fvb; mode = 2; }
    else               { A16 = x1b; W = Wo; bias = bo_; outf = xout; mode = 3; }

    const int t    = threadIdx.x;
    const int lane = t & 63;
    const int wv   = t >> 6;
    const int wr   = wv >> 1, wc = wv & 1;
    const int m16  = lane & 15, q4 = lane >> 4;
    const int m0   = blockIdx.y * 128;
    const int n0   = blockIdx.x * 128;

    f32x4 acc[4][4] = {};
    for (int k0 = 0; k0 < 512; k0 += 32) {
        {
            const int sr = t >> 1, sh = t & 1;
            const int row = m0 + sr;
            ushort ta[16];
            if (A16) {
                bf16x8 z = {}; bf16x8 v0 = z, v1 = z;
                if (row < BT_) {
                    const bf16x8* gp = (const bf16x8*)(A16 + (size_t)row*512 + k0 + sh*16);
                    v0 = gp[0]; v1 = gp[1];
                }
                *(bf16x8*)&ta[0] = v0; *(bf16x8*)&ta[8] = v1;
            } else {
                #pragma unroll
                for (int e = 0; e < 16; ++e) ta[e] = 0;
                if (row < BT_) {
                    const float* ap = A32 + (size_t)row*512 + k0 + sh*16;
                    #pragma unroll
                    for (int e = 0; e < 4; ++e) {
                        float4 f = *(const float4*)(ap + e*4);
                        ta[e*4+0]=f2bf(f.x); ta[e*4+1]=f2bf(f.y);
                        ta[e*4+2]=f2bf(f.z); ta[e*4+3]=f2bf(f.w);
                    }
                }
            }
            *(bf16x8*)&As[sr*40 + sh*16]     = *(bf16x8*)&ta[0];
            *(bf16x8*)&As[sr*40 + sh*16 + 8] = *(bf16x8*)&ta[8];
            const float* wp = W + (size_t)(n0 + sr)*512 + k0 + sh*16;
            ushort tw[16];
            #pragma unroll
            for (int e = 0; e < 4; ++e) {
                float4 f = *(const float4*)(wp + e*4);
                tw[e*4+0]=f2bf(f.x); tw[e*4+1]=f2bf(f.y);
                tw[e*4+2]=f2bf(f.z); tw[e*4+3]=f2bf(f.w);
            }
            *(bf16x8*)&Bs[sr*40 + sh*16]     = *(bf16x8*)&tw[0];
            *(bf16x8*)&Bs[sr*40 + sh*16 + 8] = *(bf16x8*)&tw[8];
        }
        __syncthreads();
        bf16x8 a[4], b[4];
        #pragma unroll
        for (int i = 0; i < 4; ++i)
            a[i] = *(const bf16x8*)&As[(wr*64 + i*16 + m16)*40 + q4*8];
        #pragma unroll
        for (int j = 0; j < 4; ++j)
            b[j] = *(const bf16x8*)&Bs[(wc*64 + j*16 + m16)*40 + q4*8];
        #pragma unroll
        for (int i = 0; i < 4; ++i)
            #pragma unroll
            for (int j = 0; j < 4; ++j)
                acc[i][j] = __builtin_amdgcn_mfma_f32_16x16x32_bf16(a[i], b[j], acc[i][j], 0, 0, 0);
        __syncthreads();
    }

    #pragma unroll
    for (int j = 0; j < 4; ++j) {
        const int n = n0 + wc*64 + j*16 + m16;
        const float bn = bias[n];
        const float sc = (mode == 0) ? rel[n] * 0.125f : 1.0f;
        const int h = n >> 6, dh = n & 63;
        #pragma unroll
        for (int i = 0; i < 4; ++i) {
            #pragma unroll
            for (int r = 0; r < 4; ++r) {
                int m = m0 + wr*64 + i*16 + q4*4 + r;
                if (m >= BT_) continue;
                float v = acc[i][j][r] + bn;
                if (mode == 3) {
                    outf[(size_t)m*512 + n] = v;
                } else {
                    if (mode == 0) v *= sc;
                    int bb = m / T_, tt = m - bb*T_;
                    outb[(((size_t)bb*H_ + h)*T_ + tt)*64 + dh] = f2bf(v);
                }
            }
        }
    }
}

// ---------------------------------------------------------------------------
// Normalize col rows, gather per ids_keep (fp32, exact) AND emit f16 hi/lo
// split (x*32 = hi + lo/2048) padded to 32 dims for the MFMA gate.
// ---------------------------------------------------------------------------
__global__ void gather_norm(
    const float* __restrict__ col_head, const float* __restrict__ col_tail,
    const int* __restrict__ ids, float* __restrict__ chg, float* __restrict__ ctg,
    ushort* __restrict__ chH, ushort* __restrict__ chL,
    ushort* __restrict__ ctH, ushort* __restrict__ ctL)
{
    int r = blockIdx.x * blockDim.x + threadIdx.x;
    const int total = BH_ * T_;
    if (r >= 2*total) return;
    const bool tail = (r >= total);
    int rr = tail ? r - total : r;
    int bh = rr / T_;
    int q  = rr - bh*T_;
    int b  = bh >> 3, h = bh & 7;
    int src = (q == 0) ? 0 : (1 + ids[b*NKEEP_ + q - 1]);
    const float* cp = (tail ? col_tail : col_head) + ((size_t)h*NCOLS_ + src)*DCOL_;
    float v[DCOL_];
    float ss = 0.f;
    #pragma unroll
    for (int j = 0; j < DCOL_; ++j) { v[j] = cp[j]; ss += v[j]*v[j]; }
    float inv = 1.0f / sqrtf(ss);
    float* op = (tail ? ctg : chg) + (size_t)rr*DCOL_;
    ushort* hp = (tail ? ctH : chH) + (size_t)rr*32;
    ushort* lp = (tail ? ctL : chL) + (size_t)rr*32;
    #pragma unroll
    for (int j = 0; j < DCOL_; ++j) {
        float x = v[j]*inv;
        op[j] = x;
        float xs = x * 32.f;
        _Float16 hh = (_Float16)xs;
        float res = (xs - (float)hh) * 2048.f;
        _Float16 ll = (_Float16)res;
        hp[j] = __builtin_bit_cast(ushort, hh);
        lp[j] = __builtin_bit_cast(ushort, ll);
    }
    #pragma unroll
    for (int j = DCOL_; j < 32; ++j) { hp[j] = 0; lp[j] = 0; }
}

// ---------------------------------------------------------------------------
// Fused gate+score+exp+rowsum+PV.  R3 = exact R0 loop structure (direct
// stage-after-barrier, plain launch_bounds, identity block mapping) plus the
// two counter-proven wins from R1:
//  - gate via f16 hi/lo double-MFMA (VALUBusy 27.7->9.0 measured)
//  - Vs transpose scatter XOR-swizzled (bank conflicts 9.23M->5.09M measured)
// R1/R2's register-prefetch + __launch_bounds__(256,3) are dropped: the pair
// correlated with FETCH 71->294/365 MB, WRITE 108->184 MB (L2 thrash cliff).
// ---------------------------------------------------------------------------
__global__ __launch_bounds__(256) void fused_attn(
    const ushort* __restrict__ fhb, const ushort* __restrict__ ftb,
    const ushort* __restrict__ fvb, const float* __restrict__ chg,
    const float* __restrict__ ctg,
    const ushort* __restrict__ chH, const ushort* __restrict__ chL,
    const ushort* __restrict__ ctH, const ushort* __restrict__ ctL,
    const float* __restrict__ biasp,
    float* __restrict__ fr, ushort* __restrict__ x1b, float* __restrict__ invA)
{
    __shared__ __align__(16) ushort Qs[64*72];
    __shared__ __align__(16) ushort Ks[64*72];
    __shared__ __align__(16) ushort Vs[64*72];   // transposed [d][k], k-granule swizzled
    __shared__ __align__(16) ushort Et[64*72];   // e tile [q][k]
    __shared__ __align__(16) ushort KH[64*40];   // gate K hi (f16, 32 dims + pad)
    __shared__ __align__(16) ushort KL[64*40];   // gate K lo
    __shared__ float sumP[4*64];
    __shared__ float inv_s[64];

    const int bh = blockIdx.y;
    const int q0 = blockIdx.x * 64;

    const int t    = threadIdx.x;
    const int lane = t & 63, w = t >> 6;
    const int m16  = lane & 15, q4 = lane >> 4;
    const float bias0 = biasp[0];

    // stage Q strip (64 x 64 bf16) once
    {
        int qr = t >> 2, qc = min(q0 + qr, T_-1);
        const ushort* qp = fhb + ((size_t)bh*T_ + qc)*64 + (t&3)*16;
        *(bf16x8*)&Qs[qr*72 + (t&3)*16]     = *(const bf16x8*)qp;
        *(bf16x8*)&Qs[qr*72 + (t&3)*16 + 8] = *(const bf16x8*)(qp + 8);
    }
    // gate Q fragments (f16 hi/lo) live in registers for the whole kernel
    f16x8 gqh[4], gql[4];
    #pragma unroll
    for (int i = 0; i < 4; ++i) {
        int qc = min(q0 + i*16 + m16, T_-1);
        gqh[i] = *(const f16x8*)(chH + ((size_t)bh*T_ + qc)*32 + q4*8);
        gql[i] = *(const f16x8*)(chL + ((size_t)bh*T_ + qc)*32 + q4*8);
    }

    float psum[4][4] = {};
    f32x4 Oacc[4] = {};

    for (int kt = 0; kt < 13; ++kt) {
        const int k0g = kt*64;
        __syncthreads();   // prior tile's Et/Vs/Ks consumers done (also covers Qs on kt=0)

        // stage K, V(transposed+swizzled), KH/KL directly (R0 structure)
        {
            int kr = t >> 2, kc = min(k0g + kr, T_-1);
            const ushort* kp = ftb + ((size_t)bh*T_ + kc)*64 + (t&3)*16;
            *(bf16x8*)&Ks[kr*72 + (t&3)*16]     = *(const bf16x8*)kp;
            *(bf16x8*)&Ks[kr*72 + (t&3)*16 + 8] = *(const bf16x8*)(kp + 8);
            const ushort* vp = fvb + ((size_t)bh*T_ + kc)*64 + (t&3)*16;
            bf16x8 v0 = *(const bf16x8*)vp, v1 = *(const bf16x8*)(vp + 8);
            const int dbase = (t&3)*16;
            #pragma unroll
            for (int e = 0; e < 8; ++e) {
                int d = dbase + e;
                Vs[d*72 + (((kr>>3) ^ (d>>3))<<3) + (kr&7)] = (ushort)v0[e];
            }
            #pragma unroll
            for (int e = 0; e < 8; ++e) {
                int d = dbase + 8 + e;
                Vs[d*72 + (((kr>>3) ^ (d>>3))<<3) + (kr&7)] = (ushort)v1[e];
            }
            const ushort* hp = ctH + ((size_t)bh*T_ + kc)*32 + (t&3)*8;
            const ushort* lp = ctL + ((size_t)bh*T_ + kc)*32 + (t&3)*8;
            *(bf16x8*)&KH[kr*40 + (t&3)*8] = *(const bf16x8*)hp;
            *(bf16x8*)&KL[kr*40 + (t&3)*8] = *(const bf16x8*)lp;
        }
        __syncthreads();

        // ---- gate: f16 hi/lo double-MFMA, score*1024 = G1 + G2/2048 ----
        const int kL2 = w*16 + m16;
        const int kg  = k0g + kL2;
        unsigned kmask = 0;
        {
            f16x8 bhf = *(const f16x8*)&KH[kL2*40 + q4*8];
            f16x8 blf = *(const f16x8*)&KL[kL2*40 + q4*8];
            f32x4 G1[4] = {}; f32x4 G2[4] = {};
            #pragma unroll
            for (int i = 0; i < 4; ++i) {
                G1[i] = __builtin_amdgcn_mfma_f32_16x16x32_f16(gqh[i], bhf, G1[i], 0, 0, 0);
                G2[i] = __builtin_amdgcn_mfma_f32_16x16x32_f16(gqh[i], blf, G2[i], 0, 0, 0);
                G2[i] = __builtin_amdgcn_mfma_f32_16x16x32_f16(gql[i], bhf, G2[i], 0, 0, 0);
            }
            const bool kok = (kg != 0) && (kg < T_);
            if (kok) {
                const float bS = bias0 * 1024.f;
                #pragma unroll
                for (int i = 0; i < 4; ++i) {
                    #pragma unroll
                    for (int r = 0; r < 4; ++r) {
                        int qg = q0 + i*16 + q4*4 + r;
                        if (qg == kg) continue;
                        float sd = G1[i][r] + G2[i][r]*(1.0f/2048.0f) + bS;
                        bool keep = sd > 0.f;
                        if (__builtin_fabsf(sd) <= 0.16f && qg < T_) {
                            float s = exact_dot22(chg + ((size_t)bh*T_ + qg)*DCOL_,
                                                  ctg + ((size_t)bh*T_ + kg)*DCOL_);
                            keep = (s + bias0 > 0.f);
                        }
                        if (keep) kmask |= 1u << (i*4 + r);
                    }
                }
            }
        }

        // ---- QK^T MFMA (S tile: 64q x 16k-slice per wave) ----
        f32x4 Sacc[4] = {};
        #pragma unroll
        for (int step = 0; step < 2; ++step) {
            bf16x8 b = *(const bf16x8*)&Ks[kL2*72 + step*32 + q4*8];
            #pragma unroll
            for (int i = 0; i < 4; ++i) {
                bf16x8 a = *(const bf16x8*)&Qs[(i*16 + m16)*72 + step*32 + q4*8];
                Sacc[i] = __builtin_amdgcn_mfma_f32_16x16x32_bf16(a, b, Sacc[i], 0, 0, 0);
            }
        }

        // ---- e = keep ? exp(s) : 0 ; rowsums; Et (bf16) ----
        #pragma unroll
        for (int i = 0; i < 4; ++i) {
            #pragma unroll
            for (int r = 0; r < 4; ++r) {
                float e = ((kmask >> (i*4 + r)) & 1u) ? __expf(Sacc[i][r]) : 0.f;
                psum[i][r] += e;
                Et[(i*16 + q4*4 + r)*72 + kL2] = f2bf(e);
            }
        }
        __syncthreads();

        // ---- PV MFMA: wave w accumulates O rows w*16..+15 over 64 d ----
        #pragma unroll
        for (int step = 0; step < 2; ++step) {
            bf16x8 a = *(const bf16x8*)&Et[(w*16 + m16)*72 + step*32 + q4*8];
            #pragma unroll
            for (int j = 0; j < 4; ++j) {
                int dv = j*16 + m16;
                bf16x8 b = *(const bf16x8*)&Vs[dv*72 + (((step*4 + q4) ^ (dv>>3))<<3)];
                Oacc[j] = __builtin_amdgcn_mfma_f32_16x16x32_bf16(a, b, Oacc[j], 0, 0, 0);
            }
        }

        // ---- Et tile -> packed bf16 prefix of fr rows ----
        {
            const int c = t & 15;
            #pragma unroll
            for (int p = 0; p < 4; ++p) {
                int row = p*16 + (t >> 4);
                int qg = q0 + row;
                if (qg >= T_) continue;
                char* rowbase = (char*)(fr + ((size_t)bh*T_ + qg)*T_);
                #pragma unroll
                for (int e = 0; e < 2; ++e) {
                    int dw = c + 16*e;
                    int kk = k0g + dw*2;
                    unsigned u = *(const unsigned*)&Et[row*72 + dw*2];
                    if (kk + 1 < T_)      *(unsigned*)(rowbase + (size_t)kk*2) = u;
                    else if (kk < T_)     *(ushort*)(rowbase + (size_t)kk*2) = (ushort)u;
                }
            }
        }
    }

    // reduce rowsums over the 16 k-columns (m16) per wave
    #pragma unroll
    for (int i = 0; i < 4; ++i)
        #pragma unroll
        for (int r = 0; r < 4; ++r) {
            float v = psum[i][r];
            v += __shfl_xor(v, 1, 64);
            v += __shfl_xor(v, 2, 64);
            v += __shfl_xor(v, 4, 64);
            v += __shfl_xor(v, 8, 64);
            psum[i][r] = v;
        }
    if (m16 == 0) {
        #pragma unroll
        for (int i = 0; i < 4; ++i)
            #pragma unroll
            for (int r = 0; r < 4; ++r)
                sumP[w*64 + i*16 + q4*4 + r] = psum[i][r];
    }
    __syncthreads();
    if (t < 64) {
        float s = sumP[t] + sumP[64+t] + sumP[128+t] + sumP[192+t];
        float iv = 1.0f / fmaxf(s, 1e-30f);
        inv_s[t] = iv;
        if (q0 + t < T_) invA[(size_t)bh*T_ + q0 + t] = iv;
    }
    __syncthreads();

    // O epilogue: normalize + store x1 (bf16)
    {
        const int b = bh >> 3, h = bh & 7;
        #pragma unroll
        for (int j = 0; j < 4; ++j) {
            int d = j*16 + m16;
            #pragma unroll
            for (int r = 0; r < 4; ++r) {
                int rr = w*16 + q4*4 + r;
                int qg = q0 + rr;
                if (qg < T_)
                    x1b[((size_t)b*T_ + qg)*512 + h*64 + d] = f2bf(Oacc[j][r] * inv_s[rr]);
            }
        }
    }
}

// ---------------------------------------------------------------------------
__global__ __launch_bounds__(256) void normalize_fr(
    float* __restrict__ fr, const float* __restrict__ invA)
{
    const int row = blockIdx.x;
    const int t = threadIdx.x;
    float* rowp = fr + (size_t)row * T_;
    const ushort* packed = (const ushort*)rowp;
    const float iv = invA[row];
    float v0 = bf2f(packed[t])       * iv;
    float v1 = bf2f(packed[t + 256]) * iv;
    float v2 = bf2f(packed[t + 512]) * iv;
    float v3 = 0.f;
    if (t == 0) v3 = bf2f(packed[768]) * iv;
    __syncthreads();
    rowp[t]       = v0;
    rowp[t + 256] = v1;
    rowp[t + 512] = v2;
    if (t == 0) rowp[768] = v3;
}

// ---------------------------------------------------------------------------
extern "C" void kernel_launch(void* const* d_in, const int* in_sizes, int n_in,
                              void* d_out, int out_size, void* d_ws, size_t ws_size,
                              hipStream_t stream)
{
    (void)in_sizes; (void)n_in; (void)out_size; (void)ws_size;
    const float* x_head   = (const float*)d_in[0];
    const float* x_tail   = (const float*)d_in[1];
    const int*   ids      = (const int*)  d_in[2];
    const float* W_head_w = (const float*)d_in[3];
    const float* W_head_b = (const float*)d_in[4];
    const float* W_v_w    = (const float*)d_in[5];
    const float* W_v_b    = (const float*)d_in[6];
    const float* W_out_w  = (const float*)d_in[7];
    const float* W_out_b  = (const float*)d_in[8];
    const float* rel      = (const float*)d_in[9];
    const float* col_h    = (const float*)d_in[10];
    const float* col_t    = (const float*)d_in[11];
    const float* biasp    = (const float*)d_in[12];

    const size_t F   = (size_t)BH_*T_*64;       // 3,149,824
    const size_t C22 = (size_t)BH_*T_*DCOL_;
    const size_t C32 = (size_t)BH_*T_*32;

    char* ws = (char*)d_ws;
    ushort* fhb = (ushort*)ws;   ws += F*2;
    ushort* ftb = (ushort*)ws;   ws += F*2;
    ushort* fvb = (ushort*)ws;   ws += F*2;
    ushort* x1b = (ushort*)ws;   ws += F*2;
    float*  chg = (float*)ws;    ws += C22*4;
    float*  ctg = (float*)ws;    ws += C22*4;
    float*  invA = (float*)ws;   ws += (size_t)BH_*T_*4;
    ushort* chH = (ushort*)ws;   ws += C32*2;
    ushort* chL = (ushort*)ws;   ws += C32*2;
    ushort* ctH = (ushort*)ws;   ws += C32*2;
    ushort* ctL = (ushort*)ws;   ws += C32*2;

    float* xout = (float*)d_out;
    float* fr   = xout + (size_t)BT_*D_;

    dim3 blk(256, 1, 1);

    gather_norm<<<(2*BH_*T_ + 255)/256, blk, 0, stream>>>(
        col_h, col_t, ids, chg, ctg, chH, chL, ctH, ctL);

    proj_mfma<<<dim3(4, 49, 3), blk, 0, stream>>>(
        x_head, x_tail, nullptr, W_head_w, W_v_w, W_out_w,
        W_head_b, W_v_b, W_out_b, rel, fhb, ftb, fvb, nullptr, -1);

    fused_attn<<<dim3(13, BH_), blk, 0, stream>>>(
        fhb, ftb, fvb, chg, ctg, chH, chL, ctH, ctL, biasp, fr, x1b, invA);

    normalize_fr<<<BH_*T_, blk, 0, stream>>>(fr, invA);

    proj_mfma<<<dim3(4, 49, 1), blk, 0, stream>>>(
        x_head, x_tail, x1b, W_head_w, W_v_w, W_out_w,
        W_head_b, W_v_b, W_out_b, rel, fhb, ftb, fvb, xout, 3);
}